// Round 1
// 93.733 us; speedup vs baseline: 1.0105x; 1.0105x over previous
//
#include <hip/hip_runtime.h>

// GMP: y[n] = sum_{k,l} a[k,l] x[n-l] |x[n-l]|^k
//          + sum_{k,l,m} b[k,l,m] x[n-l] |x[n-l-m]|^k
//          + sum_{k,l,m} c[k,l,m] x[n-l] |x[n-l+m]|^k
// Ka=5,La=4; Kb=4,Lb=3,Mb=4; Kc=4,Lc=3,Mc=4; indices clipped to [0,N-1].
// out: [2,N] fp32 (re then im).

#define NTOT 1048576
#define BLOCK 256
#define EPT 4
#define TILE (BLOCK * EPT)        // 1024
#define WOFF 8                    // LDS window covers [bs-8, bs-8+NWIN)
#define NWIN (TILE + 16)          // 1040 floats (halo: -5..+3 fits in -8..+7)
#define NW4 (NWIN / 4)            // 260 float4 groups

// pad +4 floats per 32: keeps 4-aligned groups 4-aligned (ds_*_b128 legal)
// and rotates each 8-lane group across all 32 banks -> uniform bank load.
__device__ __forceinline__ int padidx4(int j) { return j + ((j >> 5) << 2); }
#define PWIN 1172                  // padidx4(1039)=1167 -> round up, 16B-friendly

__global__ void __launch_bounds__(BLOCK) gmp_kernel(
    const float* __restrict__ x_re, const float* __restrict__ x_im,
    const float* __restrict__ a_re, const float* __restrict__ a_im,
    const float* __restrict__ b_re, const float* __restrict__ b_im,
    const float* __restrict__ c_re, const float* __restrict__ c_im,
    float* __restrict__ out)
{
    __shared__ __align__(16) float s_xr[PWIN];
    __shared__ __align__(16) float s_xi[PWIN];
    __shared__ __align__(16) float s_r[PWIN];

    const int bs = blockIdx.x * TILE;
    const bool interior = (blockIdx.x != 0) && (blockIdx.x != (NTOT / TILE) - 1);

    // ---- stage tile + halo into LDS; |x| computed once per element ----
    if (interior) {
        // window base bs-8 is 16B-aligned; no index can clip -> pure float4 path
        for (int j4 = threadIdx.x; j4 < NW4; j4 += BLOCK) {
            const int g = bs - WOFF + 4 * j4;
            const float4 xr = *reinterpret_cast<const float4*>(x_re + g);
            const float4 xi = *reinterpret_cast<const float4*>(x_im + g);
            float4 rv;
            rv.x = sqrtf(fmaf(xr.x, xr.x, xi.x * xi.x));
            rv.y = sqrtf(fmaf(xr.y, xr.y, xi.y * xi.y));
            rv.z = sqrtf(fmaf(xr.z, xr.z, xi.z * xi.z));
            rv.w = sqrtf(fmaf(xr.w, xr.w, xi.w * xi.w));
            const int p = padidx4(4 * j4);
            *reinterpret_cast<float4*>(&s_xr[p]) = xr;
            *reinterpret_cast<float4*>(&s_xi[p]) = xi;
            *reinterpret_cast<float4*>(&s_r[p]) = rv;
        }
    } else {
        // first/last block: scalar path with jnp.clip semantics
        for (int j = threadIdx.x; j < NWIN; j += BLOCK) {
            int g = bs - WOFF + j;
            g = max(g, 0);
            g = min(g, NTOT - 1);
            const float xr = x_re[g];
            const float xi = x_im[g];
            const int p = padidx4(j);
            s_xr[p] = xr;
            s_xi[p] = xi;
            s_r[p] = sqrtf(fmaf(xr, xr, xi * xi));
        }
    }
    __syncthreads();

    // ---- per-thread register windows via ds_read_b128 ----
    const int t0 = threadIdx.x * EPT;   // local tile offset of first element
    // element e (global n = bs + t0 + e) needs:
    //   r at n-d, d in [-3,5]  -> window coord w = t0 + e + 8 - d in [t0+3, t0+14]
    //   x at n-l, l in [0,3]   -> w = t0 + e + 8 - l in [t0+5, t0+11]
    float rw[16];
#pragma unroll
    for (int c = 0; c < 16; c += 4) {
        const float4 v = *reinterpret_cast<const float4*>(&s_r[padidx4(t0 + c)]);
        rw[c] = v.x; rw[c + 1] = v.y; rw[c + 2] = v.z; rw[c + 3] = v.w;
    }
    float xwr[8], xwi[8];
#pragma unroll
    for (int c = 0; c < 8; c += 4) {
        const float4 vr = *reinterpret_cast<const float4*>(&s_xr[padidx4(t0 + 4 + c)]);
        const float4 vi = *reinterpret_cast<const float4*>(&s_xi[padidx4(t0 + 4 + c)]);
        xwr[c] = vr.x; xwr[c + 1] = vr.y; xwr[c + 2] = vr.z; xwr[c + 3] = vr.w;
        xwi[c] = vi.x; xwi[c + 1] = vi.y; xwi[c + 2] = vi.z; xwi[c + 3] = vi.w;
    }

    float accr[EPT], acci[EPT];
#pragma unroll
    for (int e = 0; e < EPT; ++e) { accr[e] = 0.f; acci[e] = 0.f; }

#pragma unroll
    for (int l = 0; l < 4; ++l) {
        // merged deg-4 poly in r[n-l]: a[k,l] (+ b[k,l,0] + c[k,l,0] for l<3,k<4)
        float car[5], cai[5];
#pragma unroll
        for (int k = 0; k < 5; ++k) {
            car[k] = a_re[k * 4 + l];
            cai[k] = a_im[k * 4 + l];
        }
        if (l < 3) {
#pragma unroll
            for (int k = 0; k < 4; ++k) {
                car[k] += b_re[(k * 3 + l) * 4] + c_re[(k * 3 + l) * 4];
                cai[k] += b_im[(k * 3 + l) * 4] + c_im[(k * 3 + l) * 4];
            }
        }

        float Sr[EPT], Si[EPT];
#pragma unroll
        for (int e = 0; e < EPT; ++e) {
            const float rv = rw[e + 8 - l];
            float sr = car[4], si = cai[4];
#pragma unroll
            for (int k = 3; k >= 0; --k) {
                sr = fmaf(sr, rv, car[k]);
                si = fmaf(si, rv, cai[k]);
            }
            Sr[e] = sr;
            Si[e] = si;
        }

        if (l < 3) {
#pragma unroll
            for (int m = 1; m < 4; ++m) {
                float br[4], bi[4], crr[4], cri[4];
#pragma unroll
                for (int k = 0; k < 4; ++k) {
                    br[k]  = b_re[(k * 3 + l) * 4 + m];
                    bi[k]  = b_im[(k * 3 + l) * 4 + m];
                    crr[k] = c_re[(k * 3 + l) * 4 + m];
                    cri[k] = c_im[(k * 3 + l) * 4 + m];
                }
#pragma unroll
                for (int e = 0; e < EPT; ++e) {
                    const float rb = rw[e + 8 - l - m];   // |x[n-l-m]|
                    float sr = br[3], si = bi[3];
                    sr = fmaf(sr, rb, br[2]); si = fmaf(si, rb, bi[2]);
                    sr = fmaf(sr, rb, br[1]); si = fmaf(si, rb, bi[1]);
                    sr = fmaf(sr, rb, br[0]); si = fmaf(si, rb, bi[0]);
                    Sr[e] += sr; Si[e] += si;
                    const float rc = rw[e + 8 - l + m];   // |x[n-l+m]|
                    float tr = crr[3], ti = cri[3];
                    tr = fmaf(tr, rc, crr[2]); ti = fmaf(ti, rc, cri[2]);
                    tr = fmaf(tr, rc, crr[1]); ti = fmaf(ti, rc, cri[1]);
                    tr = fmaf(tr, rc, crr[0]); ti = fmaf(ti, rc, cri[0]);
                    Sr[e] += tr; Si[e] += ti;
                }
            }
        }

        // acc += x[n-l] * S   (complex)
#pragma unroll
        for (int e = 0; e < EPT; ++e) {
            const float xrv = xwr[e + 4 - l];
            const float xiv = xwi[e + 4 - l];
            accr[e] = fmaf(xrv, Sr[e], fmaf(-xiv, Si[e], accr[e]));
            acci[e] = fmaf(xrv, Si[e], fmaf(xiv, Sr[e], acci[e]));
        }
    }

    // ---- coalesced float4 stores: out[0..N) = re, out[N..2N) = im ----
    const int n0 = bs + t0;             // multiple of 4 -> 16B aligned
    const float4 vre = make_float4(accr[0], accr[1], accr[2], accr[3]);
    const float4 vim = make_float4(acci[0], acci[1], acci[2], acci[3]);
    *reinterpret_cast<float4*>(out + n0) = vre;
    *reinterpret_cast<float4*>(out + NTOT + n0) = vim;
}

extern "C" void kernel_launch(void* const* d_in, const int* in_sizes, int n_in,
                              void* d_out, int out_size, void* d_ws, size_t ws_size,
                              hipStream_t stream)
{
    const float* x_re = (const float*)d_in[0];
    const float* x_im = (const float*)d_in[1];
    const float* a_re = (const float*)d_in[2];
    const float* a_im = (const float*)d_in[3];
    const float* b_re = (const float*)d_in[4];
    const float* b_im = (const float*)d_in[5];
    const float* c_re = (const float*)d_in[6];
    const float* c_im = (const float*)d_in[7];
    float* out = (float*)d_out;

    dim3 grid(NTOT / TILE);   // 1024 blocks, no tail
    gmp_kernel<<<grid, BLOCK, 0, stream>>>(x_re, x_im, a_re, a_im,
                                           b_re, b_im, c_re, c_im, out);
}